// Round 9
// baseline (9577.351 us; speedup 1.0000x reference)
//
#include <hip/hip_runtime.h>
#include <hip/hip_fp16.h>

typedef _Float16 f16;
typedef _Float16 half8 __attribute__((ext_vector_type(8)));
typedef float f32x4 __attribute__((ext_vector_type(4)));
typedef unsigned int u32;
typedef unsigned long long u64;
typedef unsigned short u16;

// Recurrent kernel config (round-4 verified geometry: 64 blocks = 4 groups x 16)
#define WCOLS 96           // 3 gates * 32 cols owned per block
#define WROWB 1040         // padded bytes per 512-f16 row
#define LDS_W (WCOLS * WROWB)       // 99840
#define LDS_A (16 * WROWB)          // 16640
#define LDS_H (16 * 33 * 4)         // 2112 (fp32 h blend state, block-private)
#define LDS_REC (LDS_W + LDS_A + LDS_H + 32)

// Agent-scope primitives only (round-4 proved the RMW/exchange write path).
#define A_ADD32(p, v)  __hip_atomic_fetch_add((u32*)(p), (u32)(v), __ATOMIC_RELAXED, __HIP_MEMORY_SCOPE_AGENT)
#define A_ADD64(p, v)  __hip_atomic_fetch_add((u64*)(p), (u64)(v), __ATOMIC_RELAXED, __HIP_MEMORY_SCOPE_AGENT)
#define A_LD32(p)      __hip_atomic_load((const u32*)(p), __ATOMIC_RELAXED, __HIP_MEMORY_SCOPE_AGENT)
#define A_LD64(p)      __hip_atomic_load((const u64*)(p), __ATOMIC_RELAXED, __HIP_MEMORY_SCOPE_AGENT)
#define A_XCHG64(p, v) __hip_atomic_exchange((u64*)(p), (u64)(v), __ATOMIC_RELAXED, __HIP_MEMORY_SCOPE_AGENT)

// ---------------- weight convert: W^T f16 [1536 cols][1024 k] -------------
__global__ void cvt_weights_k(const float* __restrict__ wr, const float* __restrict__ wz,
                              const float* __restrict__ wh, f16* __restrict__ WT) {
  int k = blockIdx.x;            // 0..1023
  int gate = blockIdx.y;         // 0..2
  int c = threadIdx.x;           // 0..511
  const float* w = (gate == 0) ? wr : (gate == 1) ? wz : wh;
  WT[((size_t)(gate * 512 + c)) * 1024 + k] = (f16)w[(size_t)k * 512 + c];
}

// ---------------- precompute pre[t][b][1536] = x_t @ Wx + bias (f16) ------
__global__ __launch_bounds__(256) void precompute_x_k(
    const float* __restrict__ x, const f16* __restrict__ WT,
    const float* __restrict__ br, const float* __restrict__ bz,
    const float* __restrict__ bh, f16* __restrict__ pre) {
  __shared__ char As[64 * 80];
  __shared__ char Bs[256 * 80];
  const int m0 = blockIdx.x * 64;  // m = b*512 + t
  const int n0 = blockIdx.y * 256;
  const int tid = threadIdx.x;
  const int lane = tid & 63;
  const int w = tid >> 6;
  f32x4 acc[16];
#pragma unroll
  for (int i = 0; i < 16; ++i) acc[i] = (f32x4){0.f, 0.f, 0.f, 0.f};

  for (int kk = 0; kk < 16; ++kk) {
    {
      int row = tid >> 2, kc = (tid & 3) * 8;
      const float* s = x + (size_t)(m0 + row) * 512 + kk * 32 + kc;
      float4 v0 = ((const float4*)s)[0];
      float4 v1 = ((const float4*)s)[1];
      half8 h;
      h[0] = (f16)v0.x; h[1] = (f16)v0.y; h[2] = (f16)v0.z; h[3] = (f16)v0.w;
      h[4] = (f16)v1.x; h[5] = (f16)v1.y; h[6] = (f16)v1.z; h[7] = (f16)v1.w;
      *(half8*)(As + row * 80 + kc * 2) = h;
      const uint4* bsrc = (const uint4*)(WT + ((size_t)(n0 + tid)) * 1024 + 512 + kk * 32);
      uint4* bdst = (uint4*)(Bs + tid * 80);
      bdst[0] = bsrc[0]; bdst[1] = bsrc[1]; bdst[2] = bsrc[2]; bdst[3] = bsrc[3];
    }
    __syncthreads();
    half8 a = *(const half8*)(As + (w * 16 + (lane & 15)) * 80 + (lane >> 4) * 16);
#pragma unroll
    for (int nt = 0; nt < 16; ++nt) {
      half8 b = *(const half8*)(Bs + (nt * 16 + (lane & 15)) * 80 + (lane >> 4) * 16);
      acc[nt] = __builtin_amdgcn_mfma_f32_16x16x32_f16(a, b, acc[nt], 0, 0, 0);
    }
    __syncthreads();
  }
#pragma unroll
  for (int nt = 0; nt < 16; ++nt) {
    int col = n0 + nt * 16 + (lane & 15);
    int gate = col >> 9, ci = col & 511;
    float bias = ((gate == 0) ? br : (gate == 1) ? bz : bh)[ci];
#pragma unroll
    for (int r = 0; r < 4; ++r) {
      int m = m0 + w * 16 + (lane >> 4) * 4 + r;
      int b = m >> 9, t = m & 511;
      pre[((size_t)t * 64 + b) * 1536 + col] = (f16)(acc[nt][r] + bias);
    }
  }
}

// ---------------- persistent recurrent kernel: TAGGED dataflow, no barriers
// Exchanged state is u32 = (step_tag << 16) | f16_bits, double-buffered by
// step parity. Producers: agent atomic swaps (r4-proven write path).
// Consumers: load + retry until every tag matches (staleness -> retry, never
// corruption). Tag dependency chain provides the ordering a barrier did.
__global__ __launch_bounds__(256, 1) void gru_rec_k(
    const f16* __restrict__ WT, const f16* __restrict__ pre,
    const float* __restrict__ h0, u32* hT, u32* hrT,
    u32* syncb, float* __restrict__ out) {
  extern __shared__ char smem[];
  char* Wl = smem;
  char* Al = smem + LDS_W;
  float* Hl = (float*)(smem + LDS_W + LDS_A);
  volatile int* s_misc = (int*)(smem + LDS_W + LDS_A + LDS_H);
  const int bid = blockIdx.x;
  const int g = bid & 3;
  const int cb = bid >> 2;
  const int tid = threadIdx.x;
  const int lane = tid & 63;
  const int w = tid >> 6;
  u32* abortf = syncb;
  if (tid == 0) { s_misc[0] = 0; s_misc[1] = 0; }

  // ---- weights -> LDS (one-time): 96 cols x 1024B ----
  for (int i = tid; i < WCOLS * 64; i += 256) {
    int lc = i >> 6, c16 = i & 63;
    int gate = lc / 32, ci = cb * 32 + (lc & 31);
    const uint4* s = (const uint4*)(WT + ((size_t)(gate * 512 + ci)) * 1024) + c16;
    *(uint4*)(Wl + lc * WROWB + c16 * 16) = *s;
  }
  // ---- block-private fp32 h slice -> LDS ----
  for (int i = tid; i < 16 * 32; i += 256) {
    int row = i >> 5, c = i & 31;
    Hl[row * 33 + c] = h0[(size_t)(g * 16 + row) * 512 + cb * 32 + c];
  }
  // ---- h_0 init: parity-0 buffer, tag=1 (one writer block per group) ----
  if (cb == 0) {
    u64* dst = (u64*)(hT + (size_t)g * 16 * 512);
    for (int p = tid; p < 4096; p += 256) {
      int row = p >> 8, cp = p & 255;
      const float* hp = h0 + (size_t)(g * 16 + row) * 512 + cp * 2;
      u32 lo = (u32)__builtin_bit_cast(u16, (f16)hp[0]) | (1u << 16);
      u32 hi = (u32)__builtin_bit_cast(u16, (f16)hp[1]) | (1u << 16);
      A_XCHG64(dst + p, (u64)lo | ((u64)hi << 32));
    }
  }

  // ---- per-thread constant indices ----
  const int rq = lane >> 4;                       // row quad 0..3
  const int lc1 = w * 16 + (lane & 15);           // 0..31 = r, 32..63 = z
  const int ci1 = cb * 32 + (lc1 & 31);
  const int gcol1 = (lc1 < 32) ? ci1 : (512 + ci1);
  const int lch = (w >= 2) ? ((w - 2) * 16 + (lane & 15)) : 0;
  const int ci2 = cb * 32 + lch;
  const char* Ab  = Al + (lane & 15) * WROWB + rq * 16;
  const char* Bb1 = Wl + lc1 * WROWB + rq * 16;
  const char* Bb2 = Wl + (64 + lch) * WROWB + rq * 16;
  const int srow = tid >> 4, scb = tid & 15;      // staging: row, 32-col block

  float p1r[4], p2r[4] = {0.f, 0.f, 0.f, 0.f};
  auto prefetch = [&](int t) {
#pragma unroll
    for (int r = 0; r < 4; ++r) {
      const int grow = g * 16 + rq * 4 + r;
      p1r[r] = (float)pre[((size_t)t * 64 + grow) * 1536 + gcol1];
      if (w >= 2) p2r[r] = (float)pre[((size_t)t * 64 + grow) * 1536 + 1024 + ci2];
    }
  };

  // ---- tagged staging with retry: src = group base of parity buffer ----
  auto stage = [&](const u32* src, u32 tg) -> int {
    const u64* s = (const u64*)src + (srow * 256 + scb * 16);  // 128B/thread, line-exclusive
    u64 v[16];
    const u32 pat = tg | (tg << 16);
    u32 attempts = 0;
    for (;;) {
      if (attempts < 8) {
#pragma unroll
        for (int i = 0; i < 16; ++i) v[i] = A_LD64(s + i);
      } else {   // fallback: RMW reads (r4-proven fresh); lines are thread-private
#pragma unroll
        for (int i = 0; i < 16; ++i) v[i] = A_ADD64((u64*)(s + i), 0ull);
      }
      bool ok = true;
#pragma unroll
      for (int i = 0; i < 16; ++i) {
        u32 t0 = (u32)(v[i] >> 16) & 0xffffu;
        u32 t1 = (u32)(v[i] >> 48);
        ok &= ((t0 | (t1 << 16)) == pat);
      }
      if (tid == 0) s_misc[1] = 0;
      __syncthreads();
      if (!ok) s_misc[1] = 1;
      __syncthreads();
      if (s_misc[1] == 0) break;
      ++attempts;
      if ((attempts & 63u) == 0u) {
        if (tid == 0) {
          if (A_LD32(abortf) != 0u || attempts > 30000u) {
            A_ADD32(abortf, 1u);
            s_misc[0] = 1;
          }
        }
        __syncthreads();
        if (s_misc[0]) return 1;
      }
    }
    u32 pk[16];
#pragma unroll
    for (int i = 0; i < 16; ++i)
      pk[i] = ((u32)v[i] & 0xffffu) | (((u32)(v[i] >> 32) & 0xffffu) << 16);
    char* dst = Al + srow * WROWB + scb * 64;
#pragma unroll
    for (int i = 0; i < 4; ++i) {
      uint4 q = {pk[4 * i], pk[4 * i + 1], pk[4 * i + 2], pk[4 * i + 3]};
      *(uint4*)(dst + i * 16) = q;
    }
    __syncthreads();
    return 0;
  };

  prefetch(0);

  f32x4 zreg = {0.f, 0.f, 0.f, 0.f};
  int ab = 0;
  for (int t = 0; t < 512 && !ab; ++t) {
    const u32 tg1 = (u32)t + 1u;         // tag of h_t and hr_t
    const u32 tg2 = (u32)t + 2u;         // tag of h_{t+1}
    u32* hb_r = hT  + (size_t)(t & 1) * 64 * 512 + (size_t)g * 16 * 512;
    u32* hb_w = hT  + (size_t)((t + 1) & 1) * 64 * 512 + (size_t)g * 16 * 512;
    u32* rb   = hrT + (size_t)(t & 1) * 64 * 512 + (size_t)g * 16 * 512;

    // ---- stage h_t (retry until all tags == t+1) ----
    ab = stage(hb_r, tg1);
    if (ab) break;
    // ---- phase 1: r,z = hard_sigmoid(h @ [Wr|Wz] + pre) ----
    f32x4 acc = {0.f, 0.f, 0.f, 0.f};
#pragma unroll
    for (int kk = 0; kk < 16; ++kk) {
      half8 a = *(const half8*)(Ab + kk * 64);
      half8 b = *(const half8*)(Bb1 + kk * 64);
      acc = __builtin_amdgcn_mfma_f32_16x16x32_f16(a, b, acc, 0, 0, 0);
    }
    if (lc1 < 32) {   // waves 0,1: r-gate -> tagged hr swap (2 cols / u64)
#pragma unroll
      for (int r = 0; r < 4; ++r) {
        float v = acc[r] + p1r[r];
        float gt = fmaxf(0.f, fminf(1.f, 0.2f * v + 0.5f));
        float hv = Hl[(rq * 4 + r) * 33 + (lc1 & 31)];
        u32 tv = (u32)__builtin_bit_cast(u16, (f16)(hv * gt)) | (tg1 << 16);
        u64 q = (u64)tv | (((u64)(u32)__shfl_xor((int)tv, 1, 64)) << 32);
        if (!(lane & 1)) {
          const int lr = rq * 4 + r;
          A_XCHG64((u64*)(rb + (size_t)lr * 512 + ci1), q);
        }
      }
    } else {          // waves 2,3: z-gate -> registers
#pragma unroll
      for (int r = 0; r < 4; ++r) {
        float v = acc[r] + p1r[r];
        zreg[r] = fmaxf(0.f, fminf(1.f, 0.2f * v + 0.5f));
      }
    }
    // ---- stage hr_t (tags t+1; includes own cols once swaps land) ----
    ab = stage(rb, tg1);
    if (ab) break;
    // ---- phase 2 (waves 2,3): hhat = tanh(hr @ Wh + pre); blend ----
    if (w >= 2) {
      f32x4 acc2 = {0.f, 0.f, 0.f, 0.f};
#pragma unroll
      for (int kk = 0; kk < 16; ++kk) {
        half8 a = *(const half8*)(Ab + kk * 64);
        half8 b = *(const half8*)(Bb2 + kk * 64);
        acc2 = __builtin_amdgcn_mfma_f32_16x16x32_f16(a, b, acc2, 0, 0, 0);
      }
#pragma unroll
      for (int r = 0; r < 4; ++r) {
        float v = acc2[r] + p2r[r];
        float vc = fminf(9.f, fmaxf(-9.f, v));
        float e = __expf(2.f * vc);
        float hh = (e - 1.f) * __builtin_amdgcn_rcpf(e + 1.f);
        const int row = rq * 4 + r;
        float ho = Hl[row * 33 + lch];
        float z = zreg[r];
        float hn = ho * (1.f - z) + z * hh;
        Hl[row * 33 + lch] = hn;
        u32 tv = (u32)__builtin_bit_cast(u16, (f16)hn) | (tg2 << 16);
        u64 q = (u64)tv | (((u64)(u32)__shfl_xor((int)tv, 1, 64)) << 32);
        if (!(lane & 1))
          A_XCHG64((u64*)(hb_w + (size_t)row * 512 + ci2), q);
        if (t == 511) out[(size_t)(g * 16 + row) * 512 + ci2] = hn;
      }
    }
    if (t < 511) prefetch(t + 1);   // pre[] latency hides under next retry
  }
}

// ---------------- launch ---------------------------------------------------
extern "C" void kernel_launch(void* const* d_in, const int* in_sizes, int n_in,
                              void* d_out, int out_size, void* d_ws, size_t ws_size,
                              hipStream_t stream) {
  const float* x  = (const float*)d_in[0];
  const float* h0 = (const float*)d_in[1];
  const float* wr = (const float*)d_in[2];
  const float* wz = (const float*)d_in[3];
  const float* wh = (const float*)d_in[4];
  const float* br = (const float*)d_in[5];
  const float* bz = (const float*)d_in[6];
  const float* bh = (const float*)d_in[7];
  float* out = (float*)d_out;

  char* ws = (char*)d_ws;
  size_t off = 0;
  f16* WT = (f16*)(ws + off);   off += (size_t)1536 * 1024 * 2;        // 3 MiB
  f16* pre = (f16*)(ws + off);  off += (size_t)512 * 64 * 1536 * 2;    // 96 MiB
  u32* hT  = (u32*)(ws + off);  off += (size_t)2 * 64 * 512 * 4;       // 256 KiB
  u32* hrT = (u32*)(ws + off);  off += (size_t)2 * 64 * 512 * 4;       // 256 KiB
  u32* syncb = (u32*)(ws + off); off += 4096;

  if (ws_size < off) {
    hipMemsetAsync(d_out, 0, (size_t)out_size * 4, stream);
    return;
  }

  // Clear tagged buffers + abort flag every launch (replay-safe: stale tags
  // from a previous replay would otherwise alias this run's tags).
  hipMemsetAsync(hT, 0, (size_t)2 * 2 * 64 * 512 * 4 + 4096, stream);
  cvt_weights_k<<<dim3(1024, 3), 512, 0, stream>>>(wr, wz, wh, WT);
  precompute_x_k<<<dim3(512, 6), 256, 0, stream>>>(x, WT, br, bz, bh, pre);
  hipFuncSetAttribute(reinterpret_cast<const void*>(gru_rec_k),
                      hipFuncAttributeMaxDynamicSharedMemorySize, LDS_REC);
  gru_rec_k<<<64, 256, LDS_REC, stream>>>(WT, pre, h0, hT, hrT, syncb, out);
}

// Round 10
// 3553.342 us; speedup vs baseline: 2.6953x; 2.6953x over previous
//
#include <hip/hip_runtime.h>
#include <hip/hip_fp16.h>

typedef _Float16 f16;
typedef _Float16 half8 __attribute__((ext_vector_type(8)));
typedef float f32x4 __attribute__((ext_vector_type(4)));
typedef unsigned int u32;
typedef unsigned long long u64;
typedef unsigned short u16;

// Recurrent kernel config (round-4 verified geometry)
#define WCOLS 96           // 3 gates * 32 cols owned per block
#define WROWB 1040         // padded bytes per 512-f16 row
#define LDS_W (WCOLS * WROWB)       // 99840
#define LDS_A (16 * WROWB)          // 16640
#define LDS_H (16 * 33 * 4)         // 2112 (fp32 h blend state, block-private)
#define LDS_REC (LDS_W + LDS_A + LDS_H + 16)

// Sync arrive: agent-scope RMW (round-4 proven to execute at the device
// coherence point / LLC). Data + polls: SYSTEM-scope relaxed atomics --
// documented LLVM lowering is global_load/store sc0 sc1 (bypass L1+L2,
// served by the LLC). Fresh reads with no RMW serialization, no fences.
#define A_ADD32(p, v)  __hip_atomic_fetch_add((u32*)(p), (u32)(v), __ATOMIC_RELAXED, __HIP_MEMORY_SCOPE_AGENT)
#define SYS_LD32(p)    __hip_atomic_load((const u32*)(p), __ATOMIC_RELAXED, __HIP_MEMORY_SCOPE_SYSTEM)
#define SYS_LD64(p)    __hip_atomic_load((const u64*)(p), __ATOMIC_RELAXED, __HIP_MEMORY_SCOPE_SYSTEM)
#define SYS_ST32(p, v) __hip_atomic_store((u32*)(p), (u32)(v), __ATOMIC_RELAXED, __HIP_MEMORY_SCOPE_SYSTEM)
#define SYS_ST64(p, v) __hip_atomic_store((u64*)(p), (u64)(v), __ATOMIC_RELAXED, __HIP_MEMORY_SCOPE_SYSTEM)

// ---------------- barrier: agent-RMW arrive + LLC-load poll ----------------
static __device__ __forceinline__ int gbar(u32* cnt, u32* abortf, u32 target,
                                           volatile int* s_ab) {
  __syncthreads();   // vmcnt(0) drain: all prior sc0sc1 stores acked by LLC
  if (threadIdx.x == 0) {
    A_ADD32(cnt, 1u);
    u32 it = 0;
    while (SYS_LD32(cnt) < 16u * target) {
      __builtin_amdgcn_s_sleep(1);
      if (((++it) & 63u) == 0u) {
        if (SYS_LD32(abortf) != 0u) { *s_ab = 1; break; }
        if (it > 400000u) { A_ADD32(abortf, 1u); *s_ab = 1; break; }
      }
    }
  }
  __syncthreads();
  return *s_ab;
}

// ---------------- weight convert: W^T f16 [1536 cols][1024 k] -------------
__global__ void cvt_weights_k(const float* __restrict__ wr, const float* __restrict__ wz,
                              const float* __restrict__ wh, f16* __restrict__ WT) {
  int k = blockIdx.x;            // 0..1023
  int gate = blockIdx.y;         // 0..2
  int c = threadIdx.x;           // 0..511
  const float* w = (gate == 0) ? wr : (gate == 1) ? wz : wh;
  WT[((size_t)(gate * 512 + c)) * 1024 + k] = (f16)w[(size_t)k * 512 + c];
}

// ---------------- precompute pre[t][b][1536] = x_t @ Wx + bias (f16) ------
__global__ __launch_bounds__(256) void precompute_x_k(
    const float* __restrict__ x, const f16* __restrict__ WT,
    const float* __restrict__ br, const float* __restrict__ bz,
    const float* __restrict__ bh, f16* __restrict__ pre) {
  __shared__ char As[64 * 80];
  __shared__ char Bs[256 * 80];
  const int m0 = blockIdx.x * 64;  // m = b*512 + t
  const int n0 = blockIdx.y * 256;
  const int tid = threadIdx.x;
  const int lane = tid & 63;
  const int w = tid >> 6;
  f32x4 acc[16];
#pragma unroll
  for (int i = 0; i < 16; ++i) acc[i] = (f32x4){0.f, 0.f, 0.f, 0.f};

  for (int kk = 0; kk < 16; ++kk) {
    {
      int row = tid >> 2, kc = (tid & 3) * 8;
      const float* s = x + (size_t)(m0 + row) * 512 + kk * 32 + kc;
      float4 v0 = ((const float4*)s)[0];
      float4 v1 = ((const float4*)s)[1];
      half8 h;
      h[0] = (f16)v0.x; h[1] = (f16)v0.y; h[2] = (f16)v0.z; h[3] = (f16)v0.w;
      h[4] = (f16)v1.x; h[5] = (f16)v1.y; h[6] = (f16)v1.z; h[7] = (f16)v1.w;
      *(half8*)(As + row * 80 + kc * 2) = h;
      const uint4* bsrc = (const uint4*)(WT + ((size_t)(n0 + tid)) * 1024 + 512 + kk * 32);
      uint4* bdst = (uint4*)(Bs + tid * 80);
      bdst[0] = bsrc[0]; bdst[1] = bsrc[1]; bdst[2] = bsrc[2]; bdst[3] = bsrc[3];
    }
    __syncthreads();
    half8 a = *(const half8*)(As + (w * 16 + (lane & 15)) * 80 + (lane >> 4) * 16);
#pragma unroll
    for (int nt = 0; nt < 16; ++nt) {
      half8 b = *(const half8*)(Bs + (nt * 16 + (lane & 15)) * 80 + (lane >> 4) * 16);
      acc[nt] = __builtin_amdgcn_mfma_f32_16x16x32_f16(a, b, acc[nt], 0, 0, 0);
    }
    __syncthreads();
  }
#pragma unroll
  for (int nt = 0; nt < 16; ++nt) {
    int col = n0 + nt * 16 + (lane & 15);
    int gate = col >> 9, ci = col & 511;
    float bias = ((gate == 0) ? br : (gate == 1) ? bz : bh)[ci];
#pragma unroll
    for (int r = 0; r < 4; ++r) {
      int m = m0 + w * 16 + (lane >> 4) * 4 + r;
      int b = m >> 9, t = m & 511;
      pre[((size_t)t * 64 + b) * 1536 + col] = (f16)(acc[nt][r] + bias);
    }
  }
}

// ---------------- persistent recurrent kernel -----------------------------
// grid = 64 blocks: g = bid & 3 (batch group, 16 rows), cb = bid >> 2 (cols)
__global__ __launch_bounds__(256, 1) void gru_rec_k(
    const f16* __restrict__ WT, const f16* __restrict__ pre,
    const float* __restrict__ h0, f16* h16, f16* hr16,
    u32* syncb, float* __restrict__ out) {
  extern __shared__ char smem[];
  char* Wl = smem;
  char* Al = smem + LDS_W;
  float* Hl = (float*)(smem + LDS_W + LDS_A);
  volatile int* s_ab = (int*)(smem + LDS_W + LDS_A + LDS_H);
  const int bid = blockIdx.x;
  const int g = bid & 3;
  const int cb = bid >> 2;
  const int tid = threadIdx.x;
  const int lane = tid & 63;
  const int w = tid >> 6;
  if (tid == 0) *s_ab = 0;

  u32* cnt    = syncb + g * 128;
  u32* abortf = syncb + g * 128 + 64;

  // ---- weights -> LDS (one-time): 96 cols x 1024B ----
  for (int i = tid; i < WCOLS * 64; i += 256) {
    int lc = i >> 6, c16 = i & 63;
    int gate = lc / 32, ci = cb * 32 + (lc & 31);
    const uint4* s = (const uint4*)(WT + ((size_t)(gate * 512 + ci)) * 1024) + c16;
    *(uint4*)(Wl + lc * WROWB + c16 * 16) = *s;
  }
  // ---- block-private fp32 h slice -> LDS ----
  for (int i = tid; i < 16 * 32; i += 256) {
    int row = i >> 5, c = i & 31;
    Hl[row * 33 + c] = h0[(size_t)(g * 16 + row) * 512 + cb * 32 + c];
  }
  // ---- h16 init via system stores (one writer block per group) ----
  if (cb == 0) {
    u64* dst = (u64*)(h16 + (size_t)g * 16 * 512);
    for (int i = tid; i < 2048; i += 256) {
      int e0 = i * 4;                       // first f16 element (row*512+c)
      const float* hp = h0 + (size_t)(g * 16 + (e0 >> 9)) * 512 + (e0 & 511);
      u16 b0 = __builtin_bit_cast(u16, (f16)hp[0]);
      u16 b1 = __builtin_bit_cast(u16, (f16)hp[1]);
      u16 b2 = __builtin_bit_cast(u16, (f16)hp[2]);
      u16 b3 = __builtin_bit_cast(u16, (f16)hp[3]);
      u64 v = (u64)b0 | ((u64)b1 << 16) | ((u64)b2 << 32) | ((u64)b3 << 48);
      SYS_ST64(dst + i, v);
    }
  }

  // ---- per-thread constant indices ----
  const int rq = lane >> 4;                       // row quad 0..3
  const int lc1 = w * 16 + (lane & 15);           // 0..31 = r, 32..63 = z
  const int ci1 = cb * 32 + (lc1 & 31);
  const int gcol1 = (lc1 < 32) ? ci1 : (512 + ci1);
  const int lch = (w >= 2) ? ((w - 2) * 16 + (lane & 15)) : 0;
  const int ci2 = cb * 32 + lch;
  const char* Ab  = Al + (lane & 15) * WROWB + rq * 16;
  const char* Bb1 = Wl + lc1 * WROWB + rq * 16;
  const char* Bb2 = Wl + (64 + lch) * WROWB + rq * 16;

  float p1r[4], p2r[4] = {0.f, 0.f, 0.f, 0.f};
  auto prefetch = [&](int t) {
#pragma unroll
    for (int r = 0; r < 4; ++r) {
      const int grow = g * 16 + rq * 4 + r;
      p1r[r] = (float)pre[((size_t)t * 64 + grow) * 1536 + gcol1];
      if (w >= 2) p2r[r] = (float)pre[((size_t)t * 64 + grow) * 1536 + 1024 + ci2];
    }
  };

  // ---- staging: 16KB group state -> Al via LLC-direct (sc0 sc1) loads ----
  auto stage = [&](const f16* src16) {
    const u64* s = (const u64*)src16;
    u64 tmp[8];
#pragma unroll
    for (int i = 0; i < 8; ++i) tmp[i] = SYS_LD64(s + i * 256 + tid);
#pragma unroll
    for (int i = 0; i < 8; ++i) {
      int u = i * 256 + tid;
      *(u64*)(Al + (u >> 7) * WROWB + (u & 127) * 8) = tmp[i];
    }
    __syncthreads();
  };

  prefetch(0);
  int ab = gbar(cnt, abortf, 1u, s_ab);

  f32x4 zreg = {0.f, 0.f, 0.f, 0.f};
  for (int t = 0; t < 512 && !ab; ++t) {
    // ---- stage h16[group rows] -> Al ----
    stage(h16 + (size_t)g * 16 * 512);
    // ---- phase 1: r,z = hard_sigmoid(h @ [Wr|Wz] + pre) ----
    f32x4 acc = {0.f, 0.f, 0.f, 0.f};
#pragma unroll
    for (int kk = 0; kk < 16; ++kk) {
      half8 a = *(const half8*)(Ab + kk * 64);
      half8 b = *(const half8*)(Bb1 + kk * 64);
      acc = __builtin_amdgcn_mfma_f32_16x16x32_f16(a, b, acc, 0, 0, 0);
    }
    if (lc1 < 32) {   // waves 0,1: r-gate -> hr16 (paired u32 system store)
#pragma unroll
      for (int r = 0; r < 4; ++r) {
        float v = acc[r] + p1r[r];
        float gt = fmaxf(0.f, fminf(1.f, 0.2f * v + 0.5f));
        float hv = Hl[(rq * 4 + r) * 33 + (lc1 & 31)];
        u16 hb = __builtin_bit_cast(u16, (f16)(hv * gt));
        u32 pair = (u32)hb | (((u32)(u16)__shfl_xor((int)hb, 1, 64)) << 16);
        if (!(lane & 1)) {
          const int grow = g * 16 + rq * 4 + r;
          SYS_ST32((u32*)(hr16 + (size_t)grow * 512 + ci1), pair);
        }
      }
    } else {          // waves 2,3: z-gate -> registers
#pragma unroll
      for (int r = 0; r < 4; ++r) {
        float v = acc[r] + p1r[r];
        zreg[r] = fmaxf(0.f, fminf(1.f, 0.2f * v + 0.5f));
      }
    }
    ab = gbar(cnt, abortf, 2u * t + 2u, s_ab);
    if (ab) break;
    // ---- stage hr16 -> Al ----
    stage(hr16 + (size_t)g * 16 * 512);
    // ---- phase 2 (waves 2,3): hhat = tanh(hr @ Wh + pre); blend ----
    if (w >= 2) {
      f32x4 acc2 = {0.f, 0.f, 0.f, 0.f};
#pragma unroll
      for (int kk = 0; kk < 16; ++kk) {
        half8 a = *(const half8*)(Ab + kk * 64);
        half8 b = *(const half8*)(Bb2 + kk * 64);
        acc2 = __builtin_amdgcn_mfma_f32_16x16x32_f16(a, b, acc2, 0, 0, 0);
      }
#pragma unroll
      for (int r = 0; r < 4; ++r) {
        float v = acc2[r] + p2r[r];
        float vc = fminf(9.f, fmaxf(-9.f, v));
        float e = __expf(2.f * vc);
        float hh = (e - 1.f) * __builtin_amdgcn_rcpf(e + 1.f);
        const int row = rq * 4 + r;
        float ho = Hl[row * 33 + lch];
        float z = zreg[r];
        float hn = ho * (1.f - z) + z * hh;
        Hl[row * 33 + lch] = hn;
        const int grow = g * 16 + row;
        u16 hb = __builtin_bit_cast(u16, (f16)hn);
        u32 pair = (u32)hb | (((u32)(u16)__shfl_xor((int)hb, 1, 64)) << 16);
        if (!(lane & 1))
          SYS_ST32((u32*)(h16 + (size_t)grow * 512 + ci2), pair);
        if (t == 511) out[(size_t)grow * 512 + ci2] = hn;
      }
    }
    if (t < 511) {
      prefetch(t + 1);   // pre[] latency hides in the barrier wait
      ab = gbar(cnt, abortf, 2u * t + 3u, s_ab);
    }
  }
}

// ---------------- launch ---------------------------------------------------
extern "C" void kernel_launch(void* const* d_in, const int* in_sizes, int n_in,
                              void* d_out, int out_size, void* d_ws, size_t ws_size,
                              hipStream_t stream) {
  const float* x  = (const float*)d_in[0];
  const float* h0 = (const float*)d_in[1];
  const float* wr = (const float*)d_in[2];
  const float* wz = (const float*)d_in[3];
  const float* wh = (const float*)d_in[4];
  const float* br = (const float*)d_in[5];
  const float* bz = (const float*)d_in[6];
  const float* bh = (const float*)d_in[7];
  float* out = (float*)d_out;

  char* ws = (char*)d_ws;
  size_t off = 0;
  f16* WT = (f16*)(ws + off);   off += (size_t)1536 * 1024 * 2;        // 3 MiB
  f16* pre = (f16*)(ws + off);  off += (size_t)512 * 64 * 1536 * 2;    // 96 MiB
  f16* h16 = (f16*)(ws + off);  off += (size_t)64 * 512 * 2;
  f16* hr16 = (f16*)(ws + off); off += (size_t)64 * 512 * 2;
  u32* syncb = (u32*)(ws + off); off += 8192;

  if (ws_size < off) {
    hipMemsetAsync(d_out, 0, (size_t)out_size * 4, stream);
    return;
  }

  hipMemsetAsync(syncb, 0, 8192, stream);
  cvt_weights_k<<<dim3(1024, 3), 512, 0, stream>>>(wr, wz, wh, WT);
  precompute_x_k<<<dim3(512, 6), 256, 0, stream>>>(x, WT, br, bz, bh, pre);
  hipFuncSetAttribute(reinterpret_cast<const void*>(gru_rec_k),
                      hipFuncAttributeMaxDynamicSharedMemorySize, LDS_REC);
  gru_rec_k<<<64, 256, LDS_REC, stream>>>(WT, pre, h0, h16, hr16, syncb, out);
}